// Round 11
// baseline (308.953 us; speedup 1.0000x reference)
//
#include <hip/hip_runtime.h>
#include <hip/hip_bf16.h>
#include <hip/hip_cooperative_groups.h>

namespace cg = cooperative_groups;

// Problem constants
#define BATCH     512
#define IMG       128
#define PS        8
#define GRID_P    16      // IMG/PS
#define NP        256     // GRID_P*GRID_P
#define C         128     // BOND_DIM
#define R         64      // CP_RANK
#define E         512     // EMBED_DIM

typedef float f32x4 __attribute__((ext_vector_type(4)));
typedef short s16x8 __attribute__((ext_vector_type(8)));

__device__ __forceinline__ unsigned short f2bf(float x) {
    unsigned int u = __float_as_uint(x);
    u += 0x7fffu + ((u >> 16) & 1u);          // RNE
    return (unsigned short)(u >> 16);
}
__device__ __forceinline__ float bf2f(unsigned short h) {
    return __uint_as_float(((unsigned int)h) << 16);
}

// ---------------------------------------------------------------------------
// ONE cooperative kernel, 512 blocks x 256 threads, 2 grid syncs.
//   Phase 1 (blocks 0..432): prep — WfT+pf from f0 (in-LDS transpose),
//            f1/f2/f3 -> fTL, o -> oT, Wh -> WhT.
//   Phase 2 (all 512):       level0+level1 fused (R8 structure).
//   Phase 3 (blocks 0..31):  level2+level3+LN+head+L2norm.
// LDS: single 46336 B union, phase-aliased (3 blocks/CU capacity = 768 >= 512
// so cooperative-launch occupancy validation passes with margin).
// ---------------------------------------------------------------------------
__global__ __launch_bounds__(256) void ttn_mega_kernel(
    const float* __restrict__ x,  const float* __restrict__ Wp,
    const float* __restrict__ bp, const float* __restrict__ pos,
    const float* __restrict__ gamma, const float* __restrict__ beta,
    const float* __restrict__ Wh, const float* __restrict__ bh,
    const float* __restrict__ f0, const float* __restrict__ o0,
    const float* __restrict__ f1, const float* __restrict__ o1,
    const float* __restrict__ f2, const float* __restrict__ o2,
    const float* __restrict__ f3, const float* __restrict__ o3,
    unsigned short* __restrict__ fTL, unsigned short* __restrict__ oT,
    unsigned short* __restrict__ WhT, unsigned short* __restrict__ WfT,
    float* __restrict__ pf, unsigned short* __restrict__ h2,
    float* __restrict__ out)
{
    __shared__ __align__(16) char smem[46336];
    cg::grid_group grid = cg::this_grid();

    const int bi = blockIdx.x, t = threadIdx.x;
    const int w = t >> 6, lane = t & 63;
    const int m = lane & 15, g = lane >> 4;

    // ======================= PHASE 1: prep =======================
    if (bi < 433) {
        float* ls  = (float*)smem;                 // 34816 B
        float* red = (float*)(smem + 34816);       //  1024 B

        if (bi < 256) {
            const float* src = f0 + (size_t)bi * 8192;
#pragma unroll
            for (int i = 0; i < 8; ++i) {
                const int fi = (t + 256 * i) * 4;
                const int c = fi >> 6, r = fi & 63;      // in[c][r]
                *(float4*)(ls + c * 68 + r) = *(const float4*)(src + fi);
            }
            __syncthreads();

            f32x4 acc[4];
#pragma unroll
            for (int nt = 0; nt < 4; ++nt) acc[nt] = (f32x4){0.f, 0.f, 0.f, 0.f};
#pragma unroll
            for (int kt = 0; kt < 4; ++kt) {
                s16x8 afr;
#pragma unroll
                for (int e = 0; e < 8; ++e)
                    afr[e] = (short)f2bf(ls[(kt * 32 + g * 8 + e) * 68 + w * 16 + m]);
#pragma unroll
                for (int nt = 0; nt < 4; ++nt) {
                    const float* wr = Wp + (size_t)(nt * 16 + m) * 128 + kt * 32 + g * 8;
                    const float4 b0 = *(const float4*)wr;
                    const float4 b1 = *(const float4*)(wr + 4);
                    s16x8 bfr;
                    bfr[0] = (short)f2bf(b0.x); bfr[1] = (short)f2bf(b0.y);
                    bfr[2] = (short)f2bf(b0.z); bfr[3] = (short)f2bf(b0.w);
                    bfr[4] = (short)f2bf(b1.x); bfr[5] = (short)f2bf(b1.y);
                    bfr[6] = (short)f2bf(b1.z); bfr[7] = (short)f2bf(b1.w);
                    acc[nt] = __builtin_amdgcn_mfma_f32_16x16x32_bf16(afr, bfr, acc[nt], 0, 0, 0);
                }
            }
            unsigned short* D = WfT + (size_t)bi * 4096;
#pragma unroll
            for (int nt = 0; nt < 4; ++nt)
#pragma unroll
                for (int j = 0; j < 4; ++j)
                    D[(size_t)(w * 16 + g * 4 + j) * 64 + nt * 16 + m] = f2bf(acc[nt][j]);

            {
                const int r = t & 63, half = t >> 6;
                const int n0 = bi >> 2, q = bi & 3;
                const int pp = (2 * (n0 >> 3) + (q >> 1)) * GRID_P + 2 * (n0 & 7) + (q & 1);
                const float* posr = pos + (size_t)pp * C;
                float s = 0.f;
#pragma unroll 8
                for (int e = 0; e < 32; ++e) {
                    const int c = half * 32 + e;
                    s += (posr[c] + bp[c]) * ls[c * 68 + r];
                }
                red[r * 4 + half] = s;
            }
            __syncthreads();
            if (t < 64)
                pf[bi * 64 + t] = red[t * 4 + 0] + red[t * 4 + 1] + red[t * 4 + 2] + red[t * 4 + 3];
        } else if (bi < 340) {
            const int ti = bi - 256;
            const float* src;
            if      (ti < 64) src = f1 + (size_t)ti * 8192;
            else if (ti < 80) src = f2 + (size_t)(ti - 64) * 8192;
            else              src = f3 + (size_t)(ti - 80) * 8192;
            unsigned short* dst = fTL + (size_t)ti * 8192;
#pragma unroll
            for (int i = 0; i < 8; ++i) {
                const int fi = (t + 256 * i) * 4;
                const int c = fi >> 6, r = fi & 63;
                *(float4*)(ls + c * 68 + r) = *(const float4*)(src + fi);
            }
            __syncthreads();
            const int rr = t >> 2, seg = t & 3;
            unsigned int* d32 = (unsigned int*)(dst + rr * 128 + seg * 32);
#pragma unroll
            for (int ii = 0; ii < 16; ++ii) {
                const int c = seg * 32 + ii * 2;
                const unsigned int lo = f2bf(ls[c * 68 + rr]);
                const unsigned int hi = f2bf(ls[(c + 1) * 68 + rr]);
                d32[ii] = lo | (hi << 16);
            }
        } else if (bi < 425) {
            const int oi = bi - 340;
            const float* src;
            if      (oi < 64) src = o0 + (size_t)oi * 8192;
            else if (oi < 80) src = o1 + (size_t)(oi - 64) * 8192;
            else if (oi < 84) src = o2 + (size_t)(oi - 80) * 8192;
            else              src = o3 + (size_t)(oi - 84) * 8192;
            unsigned short* dst = oT + (size_t)oi * 8192;
#pragma unroll
            for (int i = 0; i < 8; ++i) {
                const int fi = (t + 256 * i) * 4;
                const int r = fi >> 7, c = fi & 127;
                *(float4*)(ls + r * 132 + c) = *(const float4*)(src + fi);
            }
            __syncthreads();
            const int cc = t >> 1, seg = t & 1;
            unsigned int* d32 = (unsigned int*)(dst + cc * 64 + seg * 32);
#pragma unroll
            for (int ii = 0; ii < 16; ++ii) {
                const int r = seg * 32 + ii * 2;
                const unsigned int lo = f2bf(ls[r * 132 + cc]);
                const unsigned int hi = f2bf(ls[(r + 1) * 132 + cc]);
                d32[ii] = lo | (hi << 16);
            }
        } else {
            const int j = bi - 425;
#pragma unroll
            for (int i = 0; i < 8; ++i) {
                const int fi = (t + 256 * i) * 4;
                const int c = fi >> 6, e = fi & 63;
                *(float4*)(ls + c * 68 + e) = *(const float4*)(Wh + (size_t)c * E + j * 64 + e);
            }
            __syncthreads();
            const int rr = t >> 2, seg = t & 3;
            unsigned int* d32 = (unsigned int*)(WhT + (size_t)(j * 64 + rr) * 128 + seg * 32);
#pragma unroll
            for (int ii = 0; ii < 16; ++ii) {
                const int c = seg * 32 + ii * 2;
                const unsigned int lo = f2bf(ls[c * 68 + rr]);
                const unsigned int hi = f2bf(ls[(c + 1) * 68 + rr]);
                d32[ii] = lo | (hi << 16);
            }
        }
    }
    grid.sync();

    // ======================= PHASE 2: level0+level1 =======================
    {
        // union layout: pixs [0,32832) dead after A-frag loads; then
        // us1 [0,17408) ps0 [17408,26624) ps1 [26624,28928) h1s [28928,46336)
        unsigned short* pixs = (unsigned short*)smem;
        float*          us1  = (float*)smem;
        unsigned short* ps0  = (unsigned short*)(smem + 17408);
        unsigned short* ps1  = (unsigned short*)(smem + 26624);
        unsigned short* h1s  = (unsigned short*)(smem + 28928);

        const int n1 = bi >> 5, btile = bi & 31;
        const int bt = btile * 16;
        const int y1g = n1 >> 2, x1g = n1 & 3;
        const int Ry0 = y1g * 32, Rx0 = x1g * 32;
        const int n0 = (2 * y1g + (w >> 1)) * 8 + 2 * x1g + (w & 1);

        // ---- stage pixel region: 16 iters, fully line-coalesced ----
#pragma unroll
        for (int i = 0; i < 16; ++i) {
            const int idx = i * 256 + t;
            const int c4 = idx & 7, rowg = (idx >> 3) & 31, bl = idx >> 8;
            const float4 p4 = *(const float4*)(x + ((size_t)(bt + bl) * IMG + Ry0 + rowg) * IMG + Rx0 + c4 * 4);
            uint2 v;
            v.x = (unsigned int)f2bf(p4.x) | ((unsigned int)f2bf(p4.y) << 16);
            v.y = (unsigned int)f2bf(p4.z) | ((unsigned int)f2bf(p4.w) << 16);
            *(uint2*)(pixs + bl * 1026 + rowg * 32 + c4 * 4) = v;
        }
        __syncthreads();

        // ---- A-fragments from LDS ----
        s16x8 a[4][2];
        {
            const int rbase = 16 * (w >> 1);
            const int cbase = 16 * (w & 1);
#pragma unroll
            for (int q = 0; q < 4; ++q) {
                const int rq = rbase + 8 * (q >> 1) + g;
                const int cc = cbase + 8 * (q & 1);
#pragma unroll
                for (int kt = 0; kt < 2; ++kt)
                    a[q][kt] = *(const s16x8*)(pixs + m * 1026 + (rq + kt * 4) * 32 + cc);
            }
        }
        __syncthreads();   // pixs now dead; union region reusable

        // ---- level0 u-phase (+pf init) ----
        f32x4 accu[4][4];
#pragma unroll
        for (int q = 0; q < 4; ++q) {
            const float* pfq = pf + (size_t)(n0 * 4 + q) * 64;
#pragma unroll
            for (int nt = 0; nt < 4; ++nt) {
                const float pv = pfq[nt * 16 + m];
                accu[q][nt] = (f32x4){pv, pv, pv, pv};
            }
        }
#pragma unroll
        for (int q = 0; q < 4; ++q) {
            const unsigned short* Wq = WfT + (size_t)(n0 * 4 + q) * 4096;
#pragma unroll
            for (int kt = 0; kt < 2; ++kt) {
                const int koff = kt * 32 + g * 8;
#pragma unroll
                for (int nt = 0; nt < 4; ++nt) {
                    const s16x8 bfr = *(const s16x8*)(Wq + (size_t)(nt * 16 + m) * 64 + koff);
                    accu[q][nt] = __builtin_amdgcn_mfma_f32_16x16x32_bf16(a[q][kt], bfr, accu[q][nt], 0, 0, 0);
                }
            }
        }

        // ---- level0 p-phase + wave-private ps roundtrip ----
        unsigned short* myps = ps0 + w * (16 * 72);
#pragma unroll
        for (int nt = 0; nt < 4; ++nt) {
            const f32x4 pr = accu[0][nt] * accu[1][nt] * accu[2][nt] * accu[3][nt];
#pragma unroll
            for (int j = 0; j < 4; ++j)
                myps[(g * 4 + j) * 72 + nt * 16 + m] = f2bf(pr[j]);
        }

        // ---- level0 o-phase -> h1 tile in wave-private LDS ----
        {
            s16x8 ap[2];
#pragma unroll
            for (int kt = 0; kt < 2; ++kt)
                ap[kt] = *(const s16x8*)(myps + m * 72 + kt * 32 + g * 8);
            const unsigned short* oTn = oT + (size_t)n0 * 8192;
            unsigned short* myh = h1s + w * (16 * 136);
#pragma unroll
            for (int ct = 0; ct < 8; ++ct) {
                f32x4 aco = (f32x4){0.f, 0.f, 0.f, 0.f};
#pragma unroll
                for (int kt = 0; kt < 2; ++kt) {
                    const s16x8 bfr = *(const s16x8*)(oTn + (size_t)(ct * 16 + m) * 64 + kt * 32 + g * 8);
                    aco = __builtin_amdgcn_mfma_f32_16x16x32_bf16(ap[kt], bfr, aco, 0, 0, 0);
                }
#pragma unroll
                for (int j = 0; j < 4; ++j)
                    myh[(g * 4 + j) * 136 + ct * 16 + m] = f2bf(aco[j]);
            }
        }

        // ---- level1 u-phase: A = own h1 tile ----
        {
            const unsigned short* myh = h1s + w * (16 * 136);
            const unsigned short* fq = fTL + (size_t)(n1 * 4 + w) * 8192;
            f32x4 au[4];
#pragma unroll
            for (int nt = 0; nt < 4; ++nt) au[nt] = (f32x4){0.f, 0.f, 0.f, 0.f};
#pragma unroll
            for (int kt = 0; kt < 4; ++kt) {
                const int koff = kt * 32 + g * 8;
                const s16x8 afr = *(const s16x8*)(myh + m * 136 + koff);
#pragma unroll
                for (int nt = 0; nt < 4; ++nt) {
                    const s16x8 bfr = *(const s16x8*)(fq + (size_t)(nt * 16 + m) * 128 + koff);
                    au[nt] = __builtin_amdgcn_mfma_f32_16x16x32_bf16(afr, bfr, au[nt], 0, 0, 0);
                }
            }
#pragma unroll
            for (int nt = 0; nt < 4; ++nt)
#pragma unroll
                for (int j = 0; j < 4; ++j)
                    us1[(w * 16 + g * 4 + j) * 68 + nt * 16 + m] = au[nt][j];
        }
        __syncthreads();

        // ---- level1 p-phase ----
        {
            const int pb = t >> 4, r0 = (t & 15) * 4;
            const f32x4 u0 = *(const f32x4*)(us1 + (0 * 16 + pb) * 68 + r0);
            const f32x4 u1 = *(const f32x4*)(us1 + (1 * 16 + pb) * 68 + r0);
            const f32x4 u2 = *(const f32x4*)(us1 + (2 * 16 + pb) * 68 + r0);
            const f32x4 u3 = *(const f32x4*)(us1 + (3 * 16 + pb) * 68 + r0);
            const f32x4 p = u0 * u1 * u2 * u3;
            uint2 v;
            v.x = (unsigned int)f2bf(p[0]) | ((unsigned int)f2bf(p[1]) << 16);
            v.y = (unsigned int)f2bf(p[2]) | ((unsigned int)f2bf(p[3]) << 16);
            *(uint2*)(ps1 + pb * 72 + r0) = v;
        }
        __syncthreads();

        // ---- level1 o-phase -> h2 ----
        {
            s16x8 ap[2];
#pragma unroll
            for (int kt = 0; kt < 2; ++kt)
                ap[kt] = *(const s16x8*)(ps1 + m * 72 + kt * 32 + g * 8);
            const unsigned short* oTn = oT + (size_t)(64 + n1) * 8192;
#pragma unroll
            for (int i = 0; i < 2; ++i) {
                const int ct = w * 2 + i;
                f32x4 aco = (f32x4){0.f, 0.f, 0.f, 0.f};
#pragma unroll
                for (int kt = 0; kt < 2; ++kt) {
                    const s16x8 bfr = *(const s16x8*)(oTn + (size_t)(ct * 16 + m) * 64 + kt * 32 + g * 8);
                    aco = __builtin_amdgcn_mfma_f32_16x16x32_bf16(ap[kt], bfr, aco, 0, 0, 0);
                }
#pragma unroll
                for (int j = 0; j < 4; ++j)
                    h2[((size_t)(bt + g * 4 + j) * 16 + n1) * C + ct * 16 + m] = f2bf(aco[j]);
            }
        }
    }
    grid.sync();

    // ======================= PHASE 3: tail =======================
    if (bi < 32) {
        // union layout: us3 [0,17408) dead after p3; h4s [0,8448)
        // hns [8448,12800) red [12800,13056) ps2 [17408,26624)
        // ps3 [26624,28928) h3s [28928,46336)
        float*          us3 = (float*)smem;
        float*          h4s = (float*)smem;
        unsigned short* hns = (unsigned short*)(smem + 8448);
        float*          red = (float*)(smem + 12800);
        unsigned short* ps2 = (unsigned short*)(smem + 17408);
        unsigned short* ps3 = (unsigned short*)(smem + 26624);
        unsigned short* h3s = (unsigned short*)(smem + 28928);

        const int bt = bi * 16;
        const unsigned short* fT2 = fTL + (size_t)64 * 8192;
        const unsigned short* fT3 = fTL + (size_t)80 * 8192;
        const unsigned short* oT2 = oT + (size_t)80 * 8192;
        const unsigned short* oT3 = oT + (size_t)84 * 8192;

        // ===== Level 2: wave w = node n2 =====
        {
            const int n2 = w;
            const int y1 = n2 >> 1, x1 = n2 & 1;
            f32x4 acc_u[4][4];
#pragma unroll
            for (int q = 0; q < 4; ++q)
#pragma unroll
                for (int nt = 0; nt < 4; ++nt) acc_u[q][nt] = (f32x4){0.f, 0.f, 0.f, 0.f};
#pragma unroll
            for (int q = 0; q < 4; ++q) {
                const int pidx = (2 * y1 + (q >> 1)) * 4 + 2 * x1 + (q & 1);
                const unsigned short* xq = h2 + ((size_t)(bt + m) * 16 + pidx) * C;
                const unsigned short* fq = fT2 + (size_t)(n2 * 4 + q) * R * C;
#pragma unroll
                for (int kt = 0; kt < 4; ++kt) {
                    const int koff = kt * 32 + g * 8;
                    const s16x8 afr = *(const s16x8*)(xq + koff);
#pragma unroll
                    for (int nt = 0; nt < 4; ++nt) {
                        const s16x8 bfr = *(const s16x8*)(fq + (size_t)(nt * 16 + m) * C + koff);
                        acc_u[q][nt] = __builtin_amdgcn_mfma_f32_16x16x32_bf16(afr, bfr, acc_u[q][nt], 0, 0, 0);
                    }
                }
            }
            unsigned short* myps = ps2 + w * 16 * 72;
#pragma unroll
            for (int nt = 0; nt < 4; ++nt) {
                const f32x4 p = acc_u[0][nt] * acc_u[1][nt] * acc_u[2][nt] * acc_u[3][nt];
#pragma unroll
                for (int j = 0; j < 4; ++j)
                    myps[(g * 4 + j) * 72 + nt * 16 + m] = f2bf(p[j]);
            }
            f32x4 aco[8];
#pragma unroll
            for (int ct = 0; ct < 8; ++ct) aco[ct] = (f32x4){0.f, 0.f, 0.f, 0.f};
            const unsigned short* oTn = oT2 + (size_t)n2 * C * R;
#pragma unroll
            for (int kt = 0; kt < 2; ++kt) {
                const int koff = kt * 32 + g * 8;
                const s16x8 afr = *(const s16x8*)(myps + m * 72 + koff);
#pragma unroll
                for (int ct = 0; ct < 8; ++ct) {
                    const s16x8 bfr = *(const s16x8*)(oTn + (size_t)(ct * 16 + m) * R + koff);
                    aco[ct] = __builtin_amdgcn_mfma_f32_16x16x32_bf16(afr, bfr, aco[ct], 0, 0, 0);
                }
            }
#pragma unroll
            for (int ct = 0; ct < 8; ++ct)
#pragma unroll
                for (int j = 0; j < 4; ++j)
                    h3s[((g * 4 + j) * 4 + n2) * 136 + ct * 16 + m] = f2bf(aco[ct][j]);
        }
        __syncthreads();

        // ===== Level 3 u: wave w = quadrant q =====
        {
            const int q = w;
            const unsigned short* fq = fT3 + (size_t)q * R * C;
            f32x4 acc_u[4];
#pragma unroll
            for (int nt = 0; nt < 4; ++nt) acc_u[nt] = (f32x4){0.f, 0.f, 0.f, 0.f};
#pragma unroll
            for (int kt = 0; kt < 4; ++kt) {
                const int koff = kt * 32 + g * 8;
                const s16x8 afr = *(const s16x8*)(h3s + (m * 4 + q) * 136 + koff);
#pragma unroll
                for (int nt = 0; nt < 4; ++nt) {
                    const s16x8 bfr = *(const s16x8*)(fq + (size_t)(nt * 16 + m) * C + koff);
                    acc_u[nt] = __builtin_amdgcn_mfma_f32_16x16x32_bf16(afr, bfr, acc_u[nt], 0, 0, 0);
                }
            }
#pragma unroll
            for (int nt = 0; nt < 4; ++nt)
#pragma unroll
                for (int j = 0; j < 4; ++j)
                    us3[(q * 16 + g * 4 + j) * 68 + nt * 16 + m] = acc_u[nt][j];
        }
        __syncthreads();
        {
            const int pb = t >> 4, r0 = (t & 15) * 4;
            const f32x4 u0 = *(const f32x4*)(us3 + (0 * 16 + pb) * 68 + r0);
            const f32x4 u1 = *(const f32x4*)(us3 + (1 * 16 + pb) * 68 + r0);
            const f32x4 u2 = *(const f32x4*)(us3 + (2 * 16 + pb) * 68 + r0);
            const f32x4 u3 = *(const f32x4*)(us3 + (3 * 16 + pb) * 68 + r0);
            const f32x4 p = u0 * u1 * u2 * u3;
            uint2 v;
            v.x = (unsigned int)f2bf(p[0]) | ((unsigned int)f2bf(p[1]) << 16);
            v.y = (unsigned int)f2bf(p[2]) | ((unsigned int)f2bf(p[3]) << 16);
            *(uint2*)(ps3 + pb * 72 + r0) = v;
        }
        __syncthreads();   // us3 dead; h4s/hns/red may now overwrite it
        {
            s16x8 ap[2];
#pragma unroll
            for (int kt = 0; kt < 2; ++kt)
                ap[kt] = *(const s16x8*)(ps3 + m * 72 + kt * 32 + g * 8);
#pragma unroll
            for (int i = 0; i < 2; ++i) {
                f32x4 aco = (f32x4){0.f, 0.f, 0.f, 0.f};
                const int ct = w * 2 + i;
#pragma unroll
                for (int kt = 0; kt < 2; ++kt) {
                    const s16x8 bfr = *(const s16x8*)(oT3 + (size_t)(ct * 16 + m) * R + kt * 32 + g * 8);
                    aco = __builtin_amdgcn_mfma_f32_16x16x32_bf16(ap[kt], bfr, aco, 0, 0, 0);
                }
#pragma unroll
                for (int j = 0; j < 4; ++j)
                    h4s[(g * 4 + j) * 132 + ct * 16 + m] = aco[j];
            }
        }
        __syncthreads();

        // ===== LayerNorm =====
        {
            const int rb = w * 4 + g;
            const int c0 = m * 8;
            const f32x4 v0 = *(const f32x4*)(h4s + rb * 132 + c0);
            const f32x4 v1 = *(const f32x4*)(h4s + rb * 132 + c0 + 4);
            float s  = v0[0] + v0[1] + v0[2] + v0[3] + v1[0] + v1[1] + v1[2] + v1[3];
            float ss = v0[0]*v0[0] + v0[1]*v0[1] + v0[2]*v0[2] + v0[3]*v0[3]
                     + v1[0]*v1[0] + v1[1]*v1[1] + v1[2]*v1[2] + v1[3]*v1[3];
#pragma unroll
            for (int off = 1; off < 16; off <<= 1) {
                s  += __shfl_xor(s, off);
                ss += __shfl_xor(ss, off);
            }
            const float mu   = s * (1.f / C);
            const float var  = ss * (1.f / C) - mu * mu;
            const float rstd = rsqrtf(var + 1e-5f);
            const f32x4 ga0 = *(const f32x4*)(gamma + c0);
            const f32x4 ga1 = *(const f32x4*)(gamma + c0 + 4);
            const f32x4 be0 = *(const f32x4*)(beta + c0);
            const f32x4 be1 = *(const f32x4*)(beta + c0 + 4);
            unsigned int o32[4];
            float hv[8];
#pragma unroll
            for (int k = 0; k < 4; ++k) hv[k]     = (v0[k] - mu) * rstd * ga0[k] + be0[k];
#pragma unroll
            for (int k = 0; k < 4; ++k) hv[4 + k] = (v1[k] - mu) * rstd * ga1[k] + be1[k];
#pragma unroll
            for (int k = 0; k < 4; ++k)
                o32[k] = (unsigned int)f2bf(hv[2*k]) | ((unsigned int)f2bf(hv[2*k+1]) << 16);
            *(uint4*)(hns + rb * 136 + c0) = *(uint4*)o32;
        }
        __syncthreads();

        // ===== Head GEMM + L2 norm =====
        {
            f32x4 acc[8];
#pragma unroll
            for (int nt = 0; nt < 8; ++nt) {
                const int e = w * 128 + nt * 16 + m;
                const float bv = bh[e];
                acc[nt] = (f32x4){bv, bv, bv, bv};
            }
#pragma unroll
            for (int kt = 0; kt < 4; ++kt) {
                const int koff = kt * 32 + g * 8;
                const s16x8 afr = *(const s16x8*)(hns + m * 136 + koff);
#pragma unroll
                for (int nt = 0; nt < 8; ++nt) {
                    const int e = w * 128 + nt * 16 + m;
                    const s16x8 bfr = *(const s16x8*)(WhT + (size_t)e * 128 + koff);
                    acc[nt] = __builtin_amdgcn_mfma_f32_16x16x32_bf16(afr, bfr, acc[nt], 0, 0, 0);
                }
            }
            float sq[4];
#pragma unroll
            for (int j = 0; j < 4; ++j) {
                float s = 0.f;
#pragma unroll
                for (int nt = 0; nt < 8; ++nt) s += acc[nt][j] * acc[nt][j];
#pragma unroll
                for (int off = 1; off < 16; off <<= 1) s += __shfl_xor(s, off);
                sq[j] = s;
            }
            if (m == 0) {
#pragma unroll
                for (int j = 0; j < 4; ++j) red[(g * 4 + j) * 4 + w] = sq[j];
            }
            __syncthreads();
#pragma unroll
            for (int j = 0; j < 4; ++j) {
                const int row = g * 4 + j;
                const float tot = red[row * 4 + 0] + red[row * 4 + 1]
                                + red[row * 4 + 2] + red[row * 4 + 3];
                const float inv = 1.f / fmaxf(sqrtf(tot), 1e-12f);
#pragma unroll
                for (int nt = 0; nt < 8; ++nt) {
                    const int e = w * 128 + nt * 16 + m;
                    out[(size_t)(bt + row) * E + e] = acc[nt][j] * inv;
                }
            }
        }
    }
}

// ---------------------------------------------------------------------------
extern "C" void kernel_launch(void* const* d_in, const int* in_sizes, int n_in,
                              void* d_out, int out_size, void* d_ws, size_t ws_size,
                              hipStream_t stream) {
    const float* x     = (const float*)d_in[0];
    const float* Wp    = (const float*)d_in[1];
    const float* bp    = (const float*)d_in[2];
    const float* pos   = (const float*)d_in[3];
    const float* gamma = (const float*)d_in[4];
    const float* beta  = (const float*)d_in[5];
    const float* Wh    = (const float*)d_in[6];
    const float* bh    = (const float*)d_in[7];
    const float* f0    = (const float*)d_in[8];
    const float* o0    = (const float*)d_in[9];
    const float* f1    = (const float*)d_in[10];
    const float* o1    = (const float*)d_in[11];
    const float* f2    = (const float*)d_in[12];
    const float* o2    = (const float*)d_in[13];
    const float* f3    = (const float*)d_in[14];
    const float* o3    = (const float*)d_in[15];
    float* out = (float*)d_out;

    // workspace layout (bf16 elements unless noted)
    unsigned short* h2  = (unsigned short*)d_ws;          // 1,048,576
    unsigned short* fTL = h2 + (size_t)1048576;           //   688,128 (84 slices)
    unsigned short* oT  = fTL + (size_t)688128;           //   696,320 (85 slices)
    unsigned short* WfT = oT + (size_t)696320;            // 1,048,576 (256 x 64x64)
    unsigned short* WhT = WfT + (size_t)1048576;          //    65,536
    float*          pff = (float*)(WhT + 65536);          //    16,384 fp32

    void* args[] = {
        (void*)&x, (void*)&Wp, (void*)&bp, (void*)&pos,
        (void*)&gamma, (void*)&beta, (void*)&Wh, (void*)&bh,
        (void*)&f0, (void*)&o0, (void*)&f1, (void*)&o1,
        (void*)&f2, (void*)&o2, (void*)&f3, (void*)&o3,
        (void*)&fTL, (void*)&oT, (void*)&WhT, (void*)&WfT,
        (void*)&pff, (void*)&h2, (void*)&out
    };
    hipLaunchCooperativeKernel((void*)ttn_mega_kernel, dim3(512), dim3(256),
                               args, 0, stream);
}

// Round 12
// 152.849 us; speedup vs baseline: 2.0213x; 2.0213x over previous
//
#include <hip/hip_runtime.h>
#include <hip/hip_bf16.h>

// Problem constants
#define BATCH     512
#define IMG       128
#define PS        8
#define GRID_P    16      // IMG/PS
#define NP        256     // GRID_P*GRID_P
#define C         128     // BOND_DIM
#define R         64      // CP_RANK
#define E         512     // EMBED_DIM

typedef float f32x4 __attribute__((ext_vector_type(4)));
typedef short s16x8 __attribute__((ext_vector_type(8)));

__device__ __forceinline__ unsigned short f2bf(float x) {
    unsigned int u = __float_as_uint(x);
    u += 0x7fffu + ((u >> 16) & 1u);          // RNE
    return (unsigned short)(u >> 16);
}
__device__ __forceinline__ float bf2f(unsigned short h) {
    return __uint_as_float(((unsigned int)h) << 16);
}

// ---------------------------------------------------------------------------
// prep_all (ONE launch, 433 blocks):
//   bi <256 : WfT+pf for level-0 slice (n0,q)=bi directly from f0 (in-LDS
//             transpose; fT0 never materialized).
//   bi 256..339 : f1/f2/f3 slices (128c x 64r) fp32 -> fTL (64r x 128c) bf16
//   bi 340..424 : o slices (64r x 128c) fp32 -> oT (128c x 64r) bf16
//   bi 425..432 : Wh (128c x 512e) -> WhT (512e x 128c) bf16
// ---------------------------------------------------------------------------
__global__ __launch_bounds__(256) void prep_all_kernel(
    const float* __restrict__ f0, const float* __restrict__ f1,
    const float* __restrict__ f2, const float* __restrict__ f3,
    const float* __restrict__ o0, const float* __restrict__ o1,
    const float* __restrict__ o2, const float* __restrict__ o3,
    const float* __restrict__ Wh, const float* __restrict__ Wp,
    const float* __restrict__ pos, const float* __restrict__ bp,
    unsigned short* __restrict__ fTL, unsigned short* __restrict__ oT,
    unsigned short* __restrict__ WhT, unsigned short* __restrict__ WfT,
    float* __restrict__ pf)
{
    __shared__ float ls[128 * 68];    // 34.8 KB
    __shared__ float red[64 * 4];
    const int bi = blockIdx.x, t = threadIdx.x;

    if (bi < 256) {
        const float* src = f0 + (size_t)bi * 8192;
#pragma unroll
        for (int i = 0; i < 8; ++i) {
            const int fi = (t + 256 * i) * 4;
            const int c = fi >> 6, r = fi & 63;      // in[c][r]
            *(float4*)(ls + c * 68 + r) = *(const float4*)(src + fi);
        }
        __syncthreads();

        const int w = t >> 6, lane = t & 63;
        const int m = lane & 15, g = lane >> 4;

        f32x4 acc[4];
#pragma unroll
        for (int nt = 0; nt < 4; ++nt) acc[nt] = (f32x4){0.f, 0.f, 0.f, 0.f};
#pragma unroll
        for (int kt = 0; kt < 4; ++kt) {
            s16x8 afr;
#pragma unroll
            for (int e = 0; e < 8; ++e)
                afr[e] = (short)f2bf(ls[(kt * 32 + g * 8 + e) * 68 + w * 16 + m]);
#pragma unroll
            for (int nt = 0; nt < 4; ++nt) {
                const float* wr = Wp + (size_t)(nt * 16 + m) * 128 + kt * 32 + g * 8;
                const float4 b0 = *(const float4*)wr;
                const float4 b1 = *(const float4*)(wr + 4);
                s16x8 bfr;
                bfr[0] = (short)f2bf(b0.x); bfr[1] = (short)f2bf(b0.y);
                bfr[2] = (short)f2bf(b0.z); bfr[3] = (short)f2bf(b0.w);
                bfr[4] = (short)f2bf(b1.x); bfr[5] = (short)f2bf(b1.y);
                bfr[6] = (short)f2bf(b1.z); bfr[7] = (short)f2bf(b1.w);
                acc[nt] = __builtin_amdgcn_mfma_f32_16x16x32_bf16(afr, bfr, acc[nt], 0, 0, 0);
            }
        }
        unsigned short* D = WfT + (size_t)bi * 4096;
#pragma unroll
        for (int nt = 0; nt < 4; ++nt)
#pragma unroll
            for (int j = 0; j < 4; ++j)
                D[(size_t)(w * 16 + g * 4 + j) * 64 + nt * 16 + m] = f2bf(acc[nt][j]);

        {
            const int r = t & 63, half = t >> 6;
            const int n0 = bi >> 2, q = bi & 3;
            const int pp = (2 * (n0 >> 3) + (q >> 1)) * GRID_P + 2 * (n0 & 7) + (q & 1);
            const float* posr = pos + (size_t)pp * C;
            float s = 0.f;
#pragma unroll 8
            for (int e = 0; e < 32; ++e) {
                const int c = half * 32 + e;
                s += (posr[c] + bp[c]) * ls[c * 68 + r];
            }
            red[r * 4 + half] = s;
        }
        __syncthreads();
        if (t < 64)
            pf[bi * 64 + t] = red[t * 4 + 0] + red[t * 4 + 1] + red[t * 4 + 2] + red[t * 4 + 3];
    } else if (bi < 340) {
        const int ti = bi - 256;
        const float* src;
        if      (ti < 64) src = f1 + (size_t)ti * 8192;
        else if (ti < 80) src = f2 + (size_t)(ti - 64) * 8192;
        else              src = f3 + (size_t)(ti - 80) * 8192;
        unsigned short* dst = fTL + (size_t)ti * 8192;
#pragma unroll
        for (int i = 0; i < 8; ++i) {
            const int fi = (t + 256 * i) * 4;
            const int c = fi >> 6, r = fi & 63;
            *(float4*)(ls + c * 68 + r) = *(const float4*)(src + fi);
        }
        __syncthreads();
        const int rr = t >> 2, seg = t & 3;
        unsigned int* d32 = (unsigned int*)(dst + rr * 128 + seg * 32);
#pragma unroll
        for (int ii = 0; ii < 16; ++ii) {
            const int c = seg * 32 + ii * 2;
            const unsigned int lo = f2bf(ls[c * 68 + rr]);
            const unsigned int hi = f2bf(ls[(c + 1) * 68 + rr]);
            d32[ii] = lo | (hi << 16);
        }
    } else if (bi < 425) {
        const int oi = bi - 340;
        const float* src;
        if      (oi < 64) src = o0 + (size_t)oi * 8192;
        else if (oi < 80) src = o1 + (size_t)(oi - 64) * 8192;
        else if (oi < 84) src = o2 + (size_t)(oi - 80) * 8192;
        else              src = o3 + (size_t)(oi - 84) * 8192;
        unsigned short* dst = oT + (size_t)oi * 8192;
#pragma unroll
        for (int i = 0; i < 8; ++i) {
            const int fi = (t + 256 * i) * 4;
            const int r = fi >> 7, c = fi & 127;
            *(float4*)(ls + r * 132 + c) = *(const float4*)(src + fi);
        }
        __syncthreads();
        const int cc = t >> 1, seg = t & 1;
        unsigned int* d32 = (unsigned int*)(dst + cc * 64 + seg * 32);
#pragma unroll
        for (int ii = 0; ii < 16; ++ii) {
            const int r = seg * 32 + ii * 2;
            const unsigned int lo = f2bf(ls[r * 132 + cc]);
            const unsigned int hi = f2bf(ls[(r + 1) * 132 + cc]);
            d32[ii] = lo | (hi << 16);
        }
    } else {
        const int j = bi - 425;
#pragma unroll
        for (int i = 0; i < 8; ++i) {
            const int fi = (t + 256 * i) * 4;
            const int c = fi >> 6, e = fi & 63;
            *(float4*)(ls + c * 68 + e) = *(const float4*)(Wh + (size_t)c * E + j * 64 + e);
        }
        __syncthreads();
        const int rr = t >> 2, seg = t & 3;
        unsigned int* d32 = (unsigned int*)(WhT + (size_t)(j * 64 + rr) * 128 + seg * 32);
#pragma unroll
        for (int ii = 0; ii < 16; ++ii) {
            const int c = seg * 32 + ii * 2;
            const unsigned int lo = f2bf(ls[c * 68 + rr]);
            const unsigned int hi = f2bf(ls[(c + 1) * 68 + rr]);
            d32[ii] = lo | (hi << 16);
        }
    }
}

// ---------------------------------------------------------------------------
// Fused level0+level1 (R8 structure, best-measured): block-cooperative LDS
// pixel staging. Block = (n1, 16 batches); 64 KB region, 128B-line-aligned.
// Staged with 16 fully-coalesced float4 iterations, bf16-converted once,
// batch stride 1026 shorts (513 dw == 1 mod 32 -> A-frag ds_read_b128
// 2-way banks = free). Wave w = child n0; level0 all in-wave; level1 via
// us1/ps1 barriers.
// ---------------------------------------------------------------------------
__global__ __launch_bounds__(256) void level01_fused(
    const float* __restrict__ x,              // (B,1,128,128)
    const unsigned short* __restrict__ WfT,   // 256 slices (64r x 64k)
    const float* __restrict__ pf,             // (256 x 64) fp32
    const unsigned short* __restrict__ oT,    // oT0 at slice n0, oT1 at 64+n1
    const unsigned short* __restrict__ fT1,   // 64 slices (64r x 128c)
    unsigned short* __restrict__ h2)          // (B,16,128) bf16
{
    __shared__ __align__(16) unsigned short pixs[16 * 1026];    // 32832 B
    __shared__ __align__(16) float          us1[4 * 16 * 68];   // 17408 B
    __shared__ __align__(16) unsigned short ps0[4 * 16 * 72];   //  9216 B
    __shared__ __align__(16) unsigned short ps1[16 * 72];       //  2304 B
    __shared__ __align__(16) unsigned short h1s[4 * 16 * 136];  // 17408 B

    const int bi = blockIdx.x;
    const int n1 = bi >> 5, btile = bi & 31;
    const int t = threadIdx.x, w = t >> 6, lane = t & 63;
    const int m = lane & 15, g = lane >> 4;
    const int bt = btile * 16;

    const int y1g = n1 >> 2, x1g = n1 & 3;
    const int Ry0 = y1g * 32, Rx0 = x1g * 32;
    const int n0 = (2 * y1g + (w >> 1)) * 8 + 2 * x1g + (w & 1);

    // ---- stage pixel region: 16 iters, fully line-coalesced ----
#pragma unroll
    for (int i = 0; i < 16; ++i) {
        const int idx = i * 256 + t;
        const int c4 = idx & 7, rowg = (idx >> 3) & 31, bl = idx >> 8;
        const float4 p4 = *(const float4*)(x + ((size_t)(bt + bl) * IMG + Ry0 + rowg) * IMG + Rx0 + c4 * 4);
        uint2 v;
        v.x = (unsigned int)f2bf(p4.x) | ((unsigned int)f2bf(p4.y) << 16);
        v.y = (unsigned int)f2bf(p4.z) | ((unsigned int)f2bf(p4.w) << 16);
        *(uint2*)(pixs + bl * 1026 + rowg * 32 + c4 * 4) = v;
    }
    __syncthreads();

    // ---- level0 pixel A-fragments from LDS ----
    s16x8 a[4][2];
    {
        const int rbase = 16 * (w >> 1);
        const int cbase = 16 * (w & 1);
#pragma unroll
        for (int q = 0; q < 4; ++q) {
            const int rq = rbase + 8 * (q >> 1) + g;
            const int cc = cbase + 8 * (q & 1);
#pragma unroll
            for (int kt = 0; kt < 2; ++kt)
                a[q][kt] = *(const s16x8*)(pixs + m * 1026 + (rq + kt * 4) * 32 + cc);
        }
    }

    // ---- level0 u-phase (+pf init), all 4 quadrants in-wave ----
    f32x4 accu[4][4];
#pragma unroll
    for (int q = 0; q < 4; ++q) {
        const float* pfq = pf + (size_t)(n0 * 4 + q) * 64;
#pragma unroll
        for (int nt = 0; nt < 4; ++nt) {
            const float pv = pfq[nt * 16 + m];
            accu[q][nt] = (f32x4){pv, pv, pv, pv};
        }
    }
#pragma unroll
    for (int q = 0; q < 4; ++q) {
        const unsigned short* Wq = WfT + (size_t)(n0 * 4 + q) * 4096;
#pragma unroll
        for (int kt = 0; kt < 2; ++kt) {
            const int koff = kt * 32 + g * 8;
#pragma unroll
            for (int nt = 0; nt < 4; ++nt) {
                const s16x8 bfr = *(const s16x8*)(Wq + (size_t)(nt * 16 + m) * 64 + koff);
                accu[q][nt] = __builtin_amdgcn_mfma_f32_16x16x32_bf16(a[q][kt], bfr, accu[q][nt], 0, 0, 0);
            }
        }
    }

    // ---- level0 p-phase (regs) + wave-private ps roundtrip ----
    unsigned short* myps = ps0 + w * (16 * 72);
#pragma unroll
    for (int nt = 0; nt < 4; ++nt) {
        const f32x4 pr = accu[0][nt] * accu[1][nt] * accu[2][nt] * accu[3][nt];
#pragma unroll
        for (int j = 0; j < 4; ++j)
            myps[(g * 4 + j) * 72 + nt * 16 + m] = f2bf(pr[j]);
    }

    // ---- level0 o-phase (in-wave) -> h1 tile in wave-private LDS ----
    {
        s16x8 ap[2];
#pragma unroll
        for (int kt = 0; kt < 2; ++kt)
            ap[kt] = *(const s16x8*)(myps + m * 72 + kt * 32 + g * 8);
        const unsigned short* oTn = oT + (size_t)n0 * 8192;
        unsigned short* myh = h1s + w * (16 * 136);
#pragma unroll
        for (int ct = 0; ct < 8; ++ct) {
            f32x4 aco = (f32x4){0.f, 0.f, 0.f, 0.f};
#pragma unroll
            for (int kt = 0; kt < 2; ++kt) {
                const s16x8 bfr = *(const s16x8*)(oTn + (size_t)(ct * 16 + m) * 64 + kt * 32 + g * 8);
                aco = __builtin_amdgcn_mfma_f32_16x16x32_bf16(ap[kt], bfr, aco, 0, 0, 0);
            }
#pragma unroll
            for (int j = 0; j < 4; ++j)
                myh[(g * 4 + j) * 136 + ct * 16 + m] = f2bf(aco[j]);
        }
    }

    // ---- level1 u-phase: A = own h1 tile (wave-private, no barrier) ----
    {
        const unsigned short* myh = h1s + w * (16 * 136);
        const unsigned short* fq = fT1 + (size_t)(n1 * 4 + w) * 8192;
        f32x4 au[4];
#pragma unroll
        for (int nt = 0; nt < 4; ++nt) au[nt] = (f32x4){0.f, 0.f, 0.f, 0.f};
#pragma unroll
        for (int kt = 0; kt < 4; ++kt) {
            const int koff = kt * 32 + g * 8;
            const s16x8 afr = *(const s16x8*)(myh + m * 136 + koff);
#pragma unroll
            for (int nt = 0; nt < 4; ++nt) {
                const s16x8 bfr = *(const s16x8*)(fq + (size_t)(nt * 16 + m) * 128 + koff);
                au[nt] = __builtin_amdgcn_mfma_f32_16x16x32_bf16(afr, bfr, au[nt], 0, 0, 0);
            }
        }
#pragma unroll
        for (int nt = 0; nt < 4; ++nt)
#pragma unroll
            for (int j = 0; j < 4; ++j)
                us1[(w * 16 + g * 4 + j) * 68 + nt * 16 + m] = au[nt][j];
    }
    __syncthreads();

    // ---- level1 p-phase (block-wide) ----
    {
        const int pb = t >> 4, r0 = (t & 15) * 4;
        const f32x4 u0 = *(const f32x4*)(us1 + (0 * 16 + pb) * 68 + r0);
        const f32x4 u1 = *(const f32x4*)(us1 + (1 * 16 + pb) * 68 + r0);
        const f32x4 u2 = *(const f32x4*)(us1 + (2 * 16 + pb) * 68 + r0);
        const f32x4 u3 = *(const f32x4*)(us1 + (3 * 16 + pb) * 68 + r0);
        const f32x4 p = u0 * u1 * u2 * u3;
        uint2 v;
        v.x = (unsigned int)f2bf(p[0]) | ((unsigned int)f2bf(p[1]) << 16);
        v.y = (unsigned int)f2bf(p[2]) | ((unsigned int)f2bf(p[3]) << 16);
        *(uint2*)(ps1 + pb * 72 + r0) = v;
    }
    __syncthreads();

    // ---- level1 o-phase: wave handles ct = 2w, 2w+1 -> h2 ----
    {
        s16x8 ap[2];
#pragma unroll
        for (int kt = 0; kt < 2; ++kt)
            ap[kt] = *(const s16x8*)(ps1 + m * 72 + kt * 32 + g * 8);
        const unsigned short* oTn = oT + (size_t)(64 + n1) * 8192;
#pragma unroll
        for (int i = 0; i < 2; ++i) {
            const int ct = w * 2 + i;
            f32x4 aco = (f32x4){0.f, 0.f, 0.f, 0.f};
#pragma unroll
            for (int kt = 0; kt < 2; ++kt) {
                const s16x8 bfr = *(const s16x8*)(oTn + (size_t)(ct * 16 + m) * 64 + kt * 32 + g * 8);
                aco = __builtin_amdgcn_mfma_f32_16x16x32_bf16(ap[kt], bfr, aco, 0, 0, 0);
            }
#pragma unroll
            for (int j = 0; j < 4; ++j)
                h2[((size_t)(bt + g * 4 + j) * 16 + n1) * C + ct * 16 + m] = f2bf(aco[j]);
        }
    }
}

// ---------------------------------------------------------------------------
// Tail: level2 + level3 + LayerNorm + head + L2norm, block = 16 batches.
// ---------------------------------------------------------------------------
__global__ __launch_bounds__(256) void tail_kernel(
    const unsigned short* __restrict__ h2,    // (B,16,128) bf16
    const unsigned short* __restrict__ fT2,   // 16 slices (64 x 128)
    const unsigned short* __restrict__ oT2,   // 4 slices (128 x 64)
    const unsigned short* __restrict__ fT3,   // 4 slices (64 x 128)
    const unsigned short* __restrict__ oT3,   // 1 slice (128 x 64)
    const float* __restrict__ gamma, const float* __restrict__ beta,
    const unsigned short* __restrict__ WhT,   // (512 x 128) bf16
    const float* __restrict__ bh,             // (512)
    float* __restrict__ out)                  // (B,512) fp32
{
    __shared__ __align__(16) float          us3[4 * 16 * 68];
    __shared__ __align__(16) unsigned short ps2[4 * 16 * 72];
    __shared__ __align__(16) unsigned short ps3[16 * 72];
    __shared__ __align__(16) unsigned short h3s[16 * 4 * 136];
    __shared__ __align__(16) float          h4s[16 * 132];
    __shared__ __align__(16) unsigned short hns[16 * 136];
    __shared__ float red[16 * 4];

    const int bt = blockIdx.x * 16;
    const int t = threadIdx.x, w = t >> 6, lane = t & 63;
    const int m = lane & 15, g = lane >> 4;

    // ===== Level 2: wave w = node n2 =====
    {
        const int n2 = w;
        const int y1 = n2 >> 1, x1 = n2 & 1;
        f32x4 acc_u[4][4];
#pragma unroll
        for (int q = 0; q < 4; ++q)
#pragma unroll
            for (int nt = 0; nt < 4; ++nt) acc_u[q][nt] = (f32x4){0.f, 0.f, 0.f, 0.f};
#pragma unroll
        for (int q = 0; q < 4; ++q) {
            const int pidx = (2 * y1 + (q >> 1)) * 4 + 2 * x1 + (q & 1);
            const unsigned short* xq = h2 + ((size_t)(bt + m) * 16 + pidx) * C;
            const unsigned short* fq = fT2 + (size_t)(n2 * 4 + q) * R * C;
#pragma unroll
            for (int kt = 0; kt < 4; ++kt) {
                const int koff = kt * 32 + g * 8;
                const s16x8 a = *(const s16x8*)(xq + koff);
#pragma unroll
                for (int nt = 0; nt < 4; ++nt) {
                    const s16x8 bfr = *(const s16x8*)(fq + (size_t)(nt * 16 + m) * C + koff);
                    acc_u[q][nt] = __builtin_amdgcn_mfma_f32_16x16x32_bf16(a, bfr, acc_u[q][nt], 0, 0, 0);
                }
            }
        }
        unsigned short* myps = ps2 + w * 16 * 72;
#pragma unroll
        for (int nt = 0; nt < 4; ++nt) {
            const f32x4 p = acc_u[0][nt] * acc_u[1][nt] * acc_u[2][nt] * acc_u[3][nt];
#pragma unroll
            for (int j = 0; j < 4; ++j)
                myps[(g * 4 + j) * 72 + nt * 16 + m] = f2bf(p[j]);
        }
        f32x4 aco[8];
#pragma unroll
        for (int ct = 0; ct < 8; ++ct) aco[ct] = (f32x4){0.f, 0.f, 0.f, 0.f};
        const unsigned short* oTn = oT2 + (size_t)n2 * C * R;
#pragma unroll
        for (int kt = 0; kt < 2; ++kt) {
            const int koff = kt * 32 + g * 8;
            const s16x8 a = *(const s16x8*)(myps + m * 72 + koff);
#pragma unroll
            for (int ct = 0; ct < 8; ++ct) {
                const s16x8 bfr = *(const s16x8*)(oTn + (size_t)(ct * 16 + m) * R + koff);
                aco[ct] = __builtin_amdgcn_mfma_f32_16x16x32_bf16(a, bfr, aco[ct], 0, 0, 0);
            }
        }
#pragma unroll
        for (int ct = 0; ct < 8; ++ct)
#pragma unroll
            for (int j = 0; j < 4; ++j)
                h3s[((g * 4 + j) * 4 + n2) * 136 + ct * 16 + m] = f2bf(aco[ct][j]);
    }
    __syncthreads();

    // ===== Level 3: wave w = quadrant q =====
    {
        const int q = w;
        const unsigned short* fq = fT3 + (size_t)q * R * C;
        f32x4 acc_u[4];
#pragma unroll
        for (int nt = 0; nt < 4; ++nt) acc_u[nt] = (f32x4){0.f, 0.f, 0.f, 0.f};
#pragma unroll
        for (int kt = 0; kt < 4; ++kt) {
            const int koff = kt * 32 + g * 8;
            const s16x8 a = *(const s16x8*)(h3s + (m * 4 + q) * 136 + koff);
#pragma unroll
            for (int nt = 0; nt < 4; ++nt) {
                const s16x8 bfr = *(const s16x8*)(fq + (size_t)(nt * 16 + m) * C + koff);
                acc_u[nt] = __builtin_amdgcn_mfma_f32_16x16x32_bf16(a, bfr, acc_u[nt], 0, 0, 0);
            }
        }
#pragma unroll
        for (int nt = 0; nt < 4; ++nt)
#pragma unroll
            for (int j = 0; j < 4; ++j)
                us3[(q * 16 + g * 4 + j) * 68 + nt * 16 + m] = acc_u[nt][j];
    }
    __syncthreads();
    {
        const int pb = t >> 4, r0 = (t & 15) * 4;
        const f32x4 u0 = *(const f32x4*)(us3 + (0 * 16 + pb) * 68 + r0);
        const f32x4 u1 = *(const f32x4*)(us3 + (1 * 16 + pb) * 68 + r0);
        const f32x4 u2 = *(const f32x4*)(us3 + (2 * 16 + pb) * 68 + r0);
        const f32x4 u3 = *(const f32x4*)(us3 + (3 * 16 + pb) * 68 + r0);
        const f32x4 p = u0 * u1 * u2 * u3;
        uint2 v;
        v.x = (unsigned int)f2bf(p[0]) | ((unsigned int)f2bf(p[1]) << 16);
        v.y = (unsigned int)f2bf(p[2]) | ((unsigned int)f2bf(p[3]) << 16);
        *(uint2*)(ps3 + pb * 72 + r0) = v;
    }
    __syncthreads();
    {
        s16x8 ap[2];
#pragma unroll
        for (int kt = 0; kt < 2; ++kt)
            ap[kt] = *(const s16x8*)(ps3 + m * 72 + kt * 32 + g * 8);
#pragma unroll
        for (int i = 0; i < 2; ++i) {
            f32x4 aco = (f32x4){0.f, 0.f, 0.f, 0.f};
            const int ct = w * 2 + i;
#pragma unroll
            for (int kt = 0; kt < 2; ++kt) {
                const s16x8 bfr = *(const s16x8*)(oT3 + (size_t)(ct * 16 + m) * R + kt * 32 + g * 8);
                aco = __builtin_amdgcn_mfma_f32_16x16x32_bf16(ap[kt], bfr, aco, 0, 0, 0);
            }
#pragma unroll
            for (int j = 0; j < 4; ++j)
                h4s[(g * 4 + j) * 132 + ct * 16 + m] = aco[j];
        }
    }
    __syncthreads();

    // ===== LayerNorm =====
    {
        const int rb = w * 4 + g;
        const int c0 = m * 8;
        const f32x4 v0 = *(const f32x4*)(h4s + rb * 132 + c0);
        const f32x4 v1 = *(const f32x4*)(h4s + rb * 132 + c0 + 4);
        float s  = v0[0] + v0[1] + v0[2] + v0[3] + v1[0] + v1[1] + v1[2] + v1[3];
        float ss = v0[0]*v0[0] + v0[1]*v0[1] + v0[2]*v0[2] + v0[3]*v0[3]
                 + v1[0]*v1[0] + v1[1]*v1[1] + v1[2]*v1[2] + v1[3]*v1[3];
#pragma unroll
        for (int off = 1; off < 16; off <<= 1) {
            s  += __shfl_xor(s, off);
            ss += __shfl_xor(ss, off);
        }
        const float mu   = s * (1.f / C);
        const float var  = ss * (1.f / C) - mu * mu;
        const float rstd = rsqrtf(var + 1e-5f);
        const f32x4 ga0 = *(const f32x4*)(gamma + c0);
        const f32x4 ga1 = *(const f32x4*)(gamma + c0 + 4);
        const f32x4 be0 = *(const f32x4*)(beta + c0);
        const f32x4 be1 = *(const f32x4*)(beta + c0 + 4);
        unsigned int o32[4];
        float hv[8];
#pragma unroll
        for (int k = 0; k < 4; ++k) hv[k]     = (v0[k] - mu) * rstd * ga0[k] + be0[k];
#pragma unroll
        for (int k = 0; k < 4; ++k) hv[4 + k] = (v1[k] - mu) * rstd * ga1[k] + be1[k];
#pragma unroll
        for (int k = 0; k < 4; ++k)
            o32[k] = (unsigned int)f2bf(hv[2*k]) | ((unsigned int)f2bf(hv[2*k+1]) << 16);
        *(uint4*)(hns + rb * 136 + c0) = *(uint4*)o32;
    }
    __syncthreads();

    // ===== Head GEMM + L2 norm =====
    {
        f32x4 acc[8];
#pragma unroll
        for (int nt = 0; nt < 8; ++nt) {
            const int e = w * 128 + nt * 16 + m;
            const float bv = bh[e];
            acc[nt] = (f32x4){bv, bv, bv, bv};
        }
#pragma unroll
        for (int kt = 0; kt < 4; ++kt) {
            const int koff = kt * 32 + g * 8;
            const s16x8 a = *(const s16x8*)(hns + m * 136 + koff);
#pragma unroll
            for (int nt = 0; nt < 8; ++nt) {
                const int e = w * 128 + nt * 16 + m;
                const s16x8 bfr = *(const s16x8*)(WhT + (size_t)e * 128 + koff);
                acc[nt] = __builtin_amdgcn_mfma_f32_16x16x32_bf16(a, bfr, acc[nt], 0, 0, 0);
            }
        }
        float sq[4];
#pragma unroll
        for (int j = 0; j < 4; ++j) {
            float s = 0.f;
#pragma unroll
            for (int nt = 0; nt < 8; ++nt) s += acc[nt][j] * acc[nt][j];
#pragma unroll
            for (int off = 1; off < 16; off <<= 1) s += __shfl_xor(s, off);
            sq[j] = s;
        }
        if (m == 0) {
#pragma unroll
            for (int j = 0; j < 4; ++j) red[(g * 4 + j) * 4 + w] = sq[j];
        }
        __syncthreads();
#pragma unroll
        for (int j = 0; j < 4; ++j) {
            const int row = g * 4 + j;
            const float tot = red[row * 4 + 0] + red[row * 4 + 1]
                            + red[row * 4 + 2] + red[row * 4 + 3];
            const float inv = 1.f / fmaxf(sqrtf(tot), 1e-12f);
#pragma unroll
            for (int nt = 0; nt < 8; ++nt) {
                const int e = w * 128 + nt * 16 + m;
                out[(size_t)(bt + row) * E + e] = acc[nt][j] * inv;
            }
        }
    }
}

// ---------------------------------------------------------------------------
extern "C" void kernel_launch(void* const* d_in, const int* in_sizes, int n_in,
                              void* d_out, int out_size, void* d_ws, size_t ws_size,
                              hipStream_t stream) {
    const float* x     = (const float*)d_in[0];
    const float* Wp    = (const float*)d_in[1];
    const float* bp    = (const float*)d_in[2];
    const float* pos   = (const float*)d_in[3];
    const float* gamma = (const float*)d_in[4];
    const float* beta  = (const float*)d_in[5];
    const float* Wh    = (const float*)d_in[6];
    const float* bh    = (const float*)d_in[7];
    const float* f0    = (const float*)d_in[8];
    const float* o0    = (const float*)d_in[9];
    const float* f1    = (const float*)d_in[10];
    const float* o1    = (const float*)d_in[11];
    const float* f2    = (const float*)d_in[12];
    const float* o2    = (const float*)d_in[13];
    const float* f3    = (const float*)d_in[14];
    const float* o3    = (const float*)d_in[15];
    float* out = (float*)d_out;

    // workspace layout (bf16 elements unless noted)
    unsigned short* h2  = (unsigned short*)d_ws;          // 1,048,576
    unsigned short* fTL = h2 + (size_t)1048576;           //   688,128 (84 slices)
    unsigned short* oT  = fTL + (size_t)688128;           //   696,320 (85 slices)
    unsigned short* WfT = oT + (size_t)696320;            // 1,048,576 (256 x 64x64)
    unsigned short* WhT = WfT + (size_t)1048576;          //    65,536
    float*          pff = (float*)(WhT + 65536);          //    16,384 fp32

    unsigned short* fT1 = fTL;
    unsigned short* fT2 = fTL + (size_t)64 * 8192;
    unsigned short* fT3 = fTL + (size_t)80 * 8192;
    unsigned short* oT2 = oT + (size_t)80 * 8192;
    unsigned short* oT3 = oT + (size_t)84 * 8192;

    prep_all_kernel<<<433, 256, 0, stream>>>(f0, f1, f2, f3, o0, o1, o2, o3,
                                             Wh, Wp, pos, bp,
                                             fTL, oT, WhT, WfT, pff);

    level01_fused<<<16 * 32, 256, 0, stream>>>(x, WfT, pff, oT, fT1, h2);

    tail_kernel<<<32, 256, 0, stream>>>(h2, fT2, oT2, fT3, oT3,
                                        gamma, beta, WhT, bh, out);
}